// Round 12
// baseline (70.139 us; speedup 1.0000x reference)
//
#include <hip/hip_runtime.h>

// PointSample: bilinear grid sample, zero border.
// features: (8,128,128,256) f32, grid: (8,16384,2) f32, out: (8,16384,256) f32.
//
// Locality-bucketed (R6-R12): points count-sorted into per-batch tiles;
// main kernel walks bucket-major, XCD-chunked (one batch per XCD).
// R11 lessons: sc1-flagged stores RAISED fetch (66->97 MB) — reverted to
// __builtin_nontemporal_store. PPW=8 with interleaved loads lost MLP — back
// to PPW=4 with the 16-load cluster.
// R12: tiles 32x32 -> 16x16 (256 KB; 64 buckets/batch) so each XCD's
// instantaneous working set (~2-3 buckets) stays L2-resident -> gathers hit
// 4 MiB L2 (34.5 TB/s) instead of L3.

constexpr int B = 8, H = 128, W = 128, C = 256, P = 16384;
constexpr int PPW = 4;                  // points per wave (main kernel)
constexpr int TS = 16;                  // tile edge in pixels
constexpr int TPS = W / TS;             // 8 tiles per side
constexpr int TPB = TPS * TPS;          // 64 tiles per batch
constexpr int NPTS = B * P;             // 131072 points
constexpr int NBLK = NPTS / (4 * PPW);  // 8192 main-kernel blocks
constexpr int SPB  = 8;                 // segments per batch
constexpr int NSEG = B * SPB;           // 64 segments
constexpr int SEGP = P / SPB;           // 2048 points per segment

typedef float f32x4 __attribute__((ext_vector_type(4)));

__device__ __forceinline__ int tile_id(float gx, float gy) {
    int ix = (int)floorf(gx * (float)W - 0.5f);
    int iy = (int)floorf(gy * (float)H - 0.5f);
    ix = min(max(ix, 0), W - 1);
    iy = min(max(iy, 0), H - 1);
    return (iy / TS) * TPS + (ix / TS);
}

// 64 blocks x 1024 threads, 2 points/thread: per-segment histogram.
__global__ __launch_bounds__(1024) void histo_kernel(
    const float* __restrict__ grid, int* __restrict__ hglob)
{
    __shared__ int h[TPB];
    const int tid = threadIdx.x;
    const int seg = blockIdx.x;
    const int base = seg * SEGP;
    if (tid < TPB) h[tid] = 0;
    __syncthreads();
    const float2* g2 = reinterpret_cast<const float2*>(grid);
    #pragma unroll
    for (int i = 0; i < 2; ++i) {
        const float2 g = g2[base + i * 1024 + tid];
        atomicAdd(&h[tile_id(g.x, g.y)], 1);
    }
    __syncthreads();
    if (tid < TPB) hglob[seg * TPB + tid] = h[tid];
}

// 64 blocks x 1024 threads: compute own bucket bases from the batch's 8x64
// histogram slice, rank via LDS atomics, write perm + sorted coords.
__global__ __launch_bounds__(1024) void scatter_kernel(
    const float* __restrict__ grid, const int* __restrict__ hglob,
    int* __restrict__ perm, float2* __restrict__ gsorted)
{
    __shared__ int h[TPB];
    __shared__ int base[TPB];
    const int tid = threadIdx.x;
    const int seg = blockIdx.x;
    const int b   = seg / SPB;
    const int sib = seg - b * SPB;            // segment index within batch
    const int pbase = seg * SEGP;

    if (tid < TPB) {
        h[tid] = 0;
        const int* hb = hglob + b * SPB * TPB;  // batch's 8x64 slice
        int tot_before = 0;                     // points in earlier tiles
        for (int t = 0; t < TPB; ++t) {
            if (t < tid) {
                int s = 0;
                #pragma unroll
                for (int q = 0; q < SPB; ++q) s += hb[q * TPB + t];
                tot_before += s;
            }
        }
        int intra = 0;                          // same tile, earlier segments
        for (int q = 0; q < sib; ++q) intra += hb[q * TPB + tid];
        base[tid] = b * P + tot_before + intra;
    }
    __syncthreads();

    const float2* g2 = reinterpret_cast<const float2*>(grid);
    #pragma unroll
    for (int i = 0; i < 2; ++i) {
        const int pt = pbase + i * 1024 + tid;
        const float2 g = g2[pt];
        const int t = tile_id(g.x, g.y);
        const int r = atomicAdd(&h[t], 1);      // LDS atomic rank
        const int pos = base[t] + r;
        perm[pos] = pt;
        gsorted[pos] = g;
    }
}

__global__ __launch_bounds__(256) void point_sample_kernel(
    const float* __restrict__ features,
    const float* __restrict__ gs,     // sorted coords, float2 per slot
    const int* __restrict__ perm,
    float* __restrict__ out)
{
    const int wave = threadIdx.x >> 6;
    const int lane = threadIdx.x & 63;
    // XCD-chunked swizzle: each XCD walks one batch of the bucket order.
    int bid = blockIdx.x;
    bid = (bid & 7) * (NBLK >> 3) + (bid >> 3);
    const int w = bid * 4 + wave;

    const int4 pv = *reinterpret_cast<const int4*>(perm + w * PPW);
    const int ptv[PPW] = {pv.x, pv.y, pv.z, pv.w};
    // coalesced sorted-coordinate loads (2 x float4 = 4 points)
    const float* gf = gs + (size_t)w * 2 * PPW;
    const float4 gA = *reinterpret_cast<const float4*>(gf);
    const float4 gB = *reinterpret_cast<const float4*>(gf + 4);
    const float gxv[PPW] = {gA.x, gA.z, gB.x, gB.z};
    const float gyv[PPW] = {gA.y, gA.w, gB.y, gB.w};
    const int c = lane * 4;

    int   off[PPW][4];
    float wgt[PPW][4];
    #pragma unroll
    for (int k = 0; k < PPW; ++k) {
        const int b = ptv[k] >> 14;
        const float x = gxv[k] * (float)W - 0.5f;
        const float y = gyv[k] * (float)H - 0.5f;
        const float fx = floorf(x), fy = floorf(y);
        const int ix = (int)fx, iy = (int)fy;
        const float frx = x - fx, fry = y - fy;

        const int x0 = min(max(ix, 0), W - 1);
        const int x1 = min(max(ix + 1, 0), W - 1);
        const int y0 = min(max(iy, 0), H - 1);
        const int y1 = min(max(iy + 1, 0), H - 1);
        const float mx0 = (ix >= 0 && ix < W)         ? 1.f : 0.f;
        const float mx1 = (ix + 1 >= 0 && ix + 1 < W) ? 1.f : 0.f;
        const float my0 = (iy >= 0 && iy < H)         ? 1.f : 0.f;
        const float my1 = (iy + 1 >= 0 && iy + 1 < H) ? 1.f : 0.f;

        wgt[k][0] = (1.f - fry) * (1.f - frx) * my0 * mx0;
        wgt[k][1] = (1.f - fry) * frx         * my0 * mx1;
        wgt[k][2] = fry         * (1.f - frx) * my1 * mx0;
        wgt[k][3] = fry         * frx         * my1 * mx1;
        const int fbase = b * (H * W * C) + c;     // < 2^25, fits int
        off[k][0] = fbase + (y0 * W + x0) * C;
        off[k][1] = fbase + (y0 * W + x1) * C;
        off[k][2] = fbase + (y1 * W + x0) * C;
        off[k][3] = fbase + (y1 * W + x1) * C;
    }

    float4 v[PPW][4];
    #pragma unroll
    for (int k = 0; k < PPW; ++k)
        #pragma unroll
        for (int j = 0; j < 4; ++j)
            v[k][j] = *reinterpret_cast<const float4*>(features + off[k][j]);

    #pragma unroll
    for (int k = 0; k < PPW; ++k) {
        f32x4 acc = (f32x4)0.f;
        #pragma unroll
        for (int j = 0; j < 4; ++j) {
            const float wq = wgt[k][j];
            acc.x += wq * v[k][j].x;
            acc.y += wq * v[k][j].y;
            acc.z += wq * v[k][j].z;
            acc.w += wq * v[k][j].w;
        }
        f32x4* op = reinterpret_cast<f32x4*>(out + (size_t)ptv[k] * C + c);
        __builtin_nontemporal_store(acc, op);
    }
}

// Fallback (identity order) if workspace is too small.
__global__ __launch_bounds__(256) void point_sample_direct(
    const float* __restrict__ features,
    const float* __restrict__ grid,
    float* __restrict__ out)
{
    const int wave = threadIdx.x >> 6;
    const int lane = threadIdx.x & 63;
    const int pt = blockIdx.x * 4 + wave;
    const int b = pt >> 14;
    const float2 g = reinterpret_cast<const float2*>(grid)[pt];
    const float x = g.x * (float)W - 0.5f;
    const float y = g.y * (float)H - 0.5f;
    const float fx = floorf(x), fy = floorf(y);
    const int ix = (int)fx, iy = (int)fy;
    const float frx = x - fx, fry = y - fy;
    const float* fb = features + (size_t)b * H * W * C;
    const int c = lane * 4;
    f32x4 acc = (f32x4)0.f;
    #pragma unroll
    for (int dy = 0; dy < 2; ++dy) {
        const int hy = iy + dy;
        const bool vy = (hy >= 0) && (hy < H);
        #pragma unroll
        for (int dx = 0; dx < 2; ++dx) {
            const int wx = ix + dx;
            if (vy && (wx >= 0) && (wx < W)) {
                const float wgt = dy ? (dx ? fry * frx : fry * (1.f - frx))
                                     : (dx ? (1.f - fry) * frx : (1.f - fry) * (1.f - frx));
                const float4 vv = *reinterpret_cast<const float4*>(
                    fb + ((size_t)hy * W + wx) * C + c);
                acc.x += wgt * vv.x; acc.y += wgt * vv.y;
                acc.z += wgt * vv.z; acc.w += wgt * vv.w;
            }
        }
    }
    f32x4* op = reinterpret_cast<f32x4*>(out + (size_t)pt * C + c);
    *op = acc;
}

extern "C" void kernel_launch(void* const* d_in, const int* in_sizes, int n_in,
                              void* d_out, int out_size, void* d_ws, size_t ws_size,
                              hipStream_t stream) {
    const float* features = (const float*)d_in[0];
    const float* grid     = (const float*)d_in[1];
    float* out            = (float*)d_out;

    // ws layout: perm (NPTS int) | gsorted (NPTS float2) | hglob (NSEG*TPB int)
    const size_t need = (size_t)NPTS * sizeof(int) +
                        (size_t)NPTS * sizeof(float2) +
                        (size_t)NSEG * TPB * sizeof(int);
    if (ws_size < need) {
        point_sample_direct<<<NPTS / 4, 256, 0, stream>>>(features, grid, out);
        return;
    }

    int*    perm    = (int*)d_ws;
    float2* gsorted = (float2*)(perm + NPTS);
    int*    hglob   = (int*)(gsorted + NPTS);

    histo_kernel  <<<NSEG, 1024, 0, stream>>>(grid, hglob);
    scatter_kernel<<<NSEG, 1024, 0, stream>>>(grid, hglob, perm, gsorted);
    point_sample_kernel<<<NBLK, 256, 0, stream>>>(
        features, reinterpret_cast<const float*>(gsorted), perm, out);
}

// Round 13
// 52.309 us; speedup vs baseline: 1.3408x; 1.3408x over previous
//
#include <hip/hip_runtime.h>

// PointSample: bilinear grid sample, zero border.
// features: (8,128,128,256) f32, grid: (8,16384,2) f32, out: (8,16384,256) f32.
//
// Locality-bucketed (R6-R13): points count-sorted into 128 buckets (8 batches
// x 16 tiles of 32x32 px); main kernel walks bucket-major, XCD-chunked (one
// batch per XCD, one ~1 MB tile at a time in its 4 MiB L2). Sort dropped
// main-kernel FETCH 222 -> 66 MB.
// Refuted: sc1/nt store flags (R11: fetch UP), PPW=8 interleaved (R11),
// 16x16 tiles (R12: main unchanged, prepass +17us serial base calc).
// R13: single-kernel prepass — each of 64 blocks re-histograms its whole
// batch (128 KB, L2-cheap) counting earlier-segment points separately,
// computes bases locally, ranks + writes its own segment (coords kept in
// registers from the histogram pass). One launch, no global sync state.

constexpr int B = 8, H = 128, W = 128, C = 256, P = 16384;
constexpr int PPW = 4;                  // points per wave (main kernel)
constexpr int TS = 32;                  // tile edge in pixels
constexpr int TPS = W / TS;             // 4 tiles per side
constexpr int TPB = TPS * TPS;          // 16 tiles per batch
constexpr int NPTS = B * P;             // 131072 points
constexpr int NBLK = NPTS / (4 * PPW);  // 8192 main-kernel blocks
constexpr int SPB  = 8;                 // segments per batch
constexpr int NSEG = B * SPB;           // 64 segments
constexpr int SEGP = P / SPB;           // 2048 points per segment

typedef float f32x4 __attribute__((ext_vector_type(4)));

__device__ __forceinline__ int tile16(float gx, float gy) {
    int ix = (int)floorf(gx * (float)W - 0.5f);
    int iy = (int)floorf(gy * (float)H - 0.5f);
    ix = min(max(ix, 0), W - 1);
    iy = min(max(iy, 0), H - 1);
    return (iy / TS) * TPS + (ix / TS);
}

// 64 blocks x 1024 threads, one block per segment. Each block histograms its
// ENTIRE batch (16 rounds x 1024 coalesced float2 loads), counting points
// that precede its segment separately (h_intra); bucket bases follow locally.
// Own-segment coords/tiles are kept in registers from the histogram pass.
__global__ __launch_bounds__(1024) void sort_kernel(
    const float* __restrict__ grid, int* __restrict__ perm,
    float2* __restrict__ gsorted)
{
    __shared__ int h_total[TPB], h_intra[TPB], h_rank[TPB], base[TPB];
    const int tid  = threadIdx.x;
    const int seg  = blockIdx.x;
    const int b    = seg >> 3;
    const int sib  = seg & 7;               // segment index within batch
    const int bbase = b * P;
    const int pbase = seg * SEGP;

    if (tid < TPB) { h_total[tid] = 0; h_intra[tid] = 0; h_rank[tid] = 0; }
    __syncthreads();

    const float2* g2 = reinterpret_cast<const float2*>(grid);
    float2 myG[2]; int myT[2];
    #pragma unroll
    for (int i = 0; i < 16; ++i) {
        const int pt = bbase + i * 1024 + tid;
        const float2 g = g2[pt];
        const int t = tile16(g.x, g.y);
        atomicAdd(&h_total[t], 1);
        if (i < sib * 2) atomicAdd(&h_intra[t], 1);   // uniform branch
        if (i == sib * 2)     { myG[0] = g; myT[0] = t; }
        if (i == sib * 2 + 1) { myG[1] = g; myT[1] = t; }
    }
    __syncthreads();

    if (tid == 0) {
        int acc = 0;
        #pragma unroll
        for (int t = 0; t < TPB; ++t) {
            base[t] = bbase + acc + h_intra[t];
            acc += h_total[t];
        }
    }
    __syncthreads();

    #pragma unroll
    for (int j = 0; j < 2; ++j) {
        const int r = atomicAdd(&h_rank[myT[j]], 1);  // LDS atomic rank
        const int pos = base[myT[j]] + r;
        perm[pos] = pbase + j * 1024 + tid;
        gsorted[pos] = myG[j];
    }
}

__global__ __launch_bounds__(256) void point_sample_kernel(
    const float* __restrict__ features,
    const float* __restrict__ gs,     // sorted coords, float2 per slot
    const int* __restrict__ perm,
    float* __restrict__ out)
{
    const int wave = threadIdx.x >> 6;
    const int lane = threadIdx.x & 63;
    // XCD-chunked swizzle: each XCD walks one batch of the bucket order.
    int bid = blockIdx.x;
    bid = (bid & 7) * (NBLK >> 3) + (bid >> 3);
    const int w = bid * 4 + wave;

    const int4 pv = *reinterpret_cast<const int4*>(perm + w * PPW);
    const int ptv[PPW] = {pv.x, pv.y, pv.z, pv.w};
    // coalesced sorted-coordinate loads (2 x float4 = 4 points)
    const float* gf = gs + (size_t)w * 2 * PPW;
    const float4 gA = *reinterpret_cast<const float4*>(gf);
    const float4 gB = *reinterpret_cast<const float4*>(gf + 4);
    const float gxv[PPW] = {gA.x, gA.z, gB.x, gB.z};
    const float gyv[PPW] = {gA.y, gA.w, gB.y, gB.w};
    const int c = lane * 4;

    int   off[PPW][4];
    float wgt[PPW][4];
    #pragma unroll
    for (int k = 0; k < PPW; ++k) {
        const int b = ptv[k] >> 14;
        const float x = gxv[k] * (float)W - 0.5f;
        const float y = gyv[k] * (float)H - 0.5f;
        const float fx = floorf(x), fy = floorf(y);
        const int ix = (int)fx, iy = (int)fy;
        const float frx = x - fx, fry = y - fy;

        const int x0 = min(max(ix, 0), W - 1);
        const int x1 = min(max(ix + 1, 0), W - 1);
        const int y0 = min(max(iy, 0), H - 1);
        const int y1 = min(max(iy + 1, 0), H - 1);
        const float mx0 = (ix >= 0 && ix < W)         ? 1.f : 0.f;
        const float mx1 = (ix + 1 >= 0 && ix + 1 < W) ? 1.f : 0.f;
        const float my0 = (iy >= 0 && iy < H)         ? 1.f : 0.f;
        const float my1 = (iy + 1 >= 0 && iy + 1 < H) ? 1.f : 0.f;

        wgt[k][0] = (1.f - fry) * (1.f - frx) * my0 * mx0;
        wgt[k][1] = (1.f - fry) * frx         * my0 * mx1;
        wgt[k][2] = fry         * (1.f - frx) * my1 * mx0;
        wgt[k][3] = fry         * frx         * my1 * mx1;
        const int fbase = b * (H * W * C) + c;     // < 2^25, fits int
        off[k][0] = fbase + (y0 * W + x0) * C;
        off[k][1] = fbase + (y0 * W + x1) * C;
        off[k][2] = fbase + (y1 * W + x0) * C;
        off[k][3] = fbase + (y1 * W + x1) * C;
    }

    float4 v[PPW][4];
    #pragma unroll
    for (int k = 0; k < PPW; ++k)
        #pragma unroll
        for (int j = 0; j < 4; ++j)
            v[k][j] = *reinterpret_cast<const float4*>(features + off[k][j]);

    #pragma unroll
    for (int k = 0; k < PPW; ++k) {
        f32x4 acc = (f32x4)0.f;
        #pragma unroll
        for (int j = 0; j < 4; ++j) {
            const float wq = wgt[k][j];
            acc.x += wq * v[k][j].x;
            acc.y += wq * v[k][j].y;
            acc.z += wq * v[k][j].z;
            acc.w += wq * v[k][j].w;
        }
        f32x4* op = reinterpret_cast<f32x4*>(out + (size_t)ptv[k] * C + c);
        __builtin_nontemporal_store(acc, op);
    }
}

// Fallback (identity order) if workspace is too small.
__global__ __launch_bounds__(256) void point_sample_direct(
    const float* __restrict__ features,
    const float* __restrict__ grid,
    float* __restrict__ out)
{
    const int wave = threadIdx.x >> 6;
    const int lane = threadIdx.x & 63;
    const int pt = blockIdx.x * 4 + wave;
    const int b = pt >> 14;
    const float2 g = reinterpret_cast<const float2*>(grid)[pt];
    const float x = g.x * (float)W - 0.5f;
    const float y = g.y * (float)H - 0.5f;
    const float fx = floorf(x), fy = floorf(y);
    const int ix = (int)fx, iy = (int)fy;
    const float frx = x - fx, fry = y - fy;
    const float* fb = features + (size_t)b * H * W * C;
    const int c = lane * 4;
    f32x4 acc = (f32x4)0.f;
    #pragma unroll
    for (int dy = 0; dy < 2; ++dy) {
        const int hy = iy + dy;
        const bool vy = (hy >= 0) && (hy < H);
        #pragma unroll
        for (int dx = 0; dx < 2; ++dx) {
            const int wx = ix + dx;
            if (vy && (wx >= 0) && (wx < W)) {
                const float wgt = dy ? (dx ? fry * frx : fry * (1.f - frx))
                                     : (dx ? (1.f - fry) * frx : (1.f - fry) * (1.f - frx));
                const float4 vv = *reinterpret_cast<const float4*>(
                    fb + ((size_t)hy * W + wx) * C + c);
                acc.x += wgt * vv.x; acc.y += wgt * vv.y;
                acc.z += wgt * vv.z; acc.w += wgt * vv.w;
            }
        }
    }
    f32x4* op = reinterpret_cast<f32x4*>(out + (size_t)pt * C + c);
    *op = acc;
}

extern "C" void kernel_launch(void* const* d_in, const int* in_sizes, int n_in,
                              void* d_out, int out_size, void* d_ws, size_t ws_size,
                              hipStream_t stream) {
    const float* features = (const float*)d_in[0];
    const float* grid     = (const float*)d_in[1];
    float* out            = (float*)d_out;

    // ws layout: perm (NPTS int) | gsorted (NPTS float2)
    const size_t need = (size_t)NPTS * sizeof(int) +
                        (size_t)NPTS * sizeof(float2);
    if (ws_size < need) {
        point_sample_direct<<<NPTS / 4, 256, 0, stream>>>(features, grid, out);
        return;
    }

    int*    perm    = (int*)d_ws;
    float2* gsorted = (float2*)(perm + NPTS);

    sort_kernel<<<NSEG, 1024, 0, stream>>>(grid, perm, gsorted);
    point_sample_kernel<<<NBLK, 256, 0, stream>>>(
        features, reinterpret_cast<const float*>(gsorted), perm, out);
}